// Round 1
// 1076.760 us; speedup vs baseline: 1.1057x; 1.1057x over previous
//
#include <hip/hip_runtime.h>

// Net_4544075399853: x->20 linear, LSTMCell(20,20), 20->1 linear; B=8192, T=2048, fp32.
// R8 (scheduling-only; per-step math bit-identical to R7):
//  - Barrier-free single-buffer LDS h-exchange. Workgroup = 1 wave => the LDS pipe
//    executes this wave's DS ops in program order, so ds_write(h_t) -> ds_read is
//    correct without __syncthreads. Removing the barrier removes the per-step
//    s_waitcnt lgkmcnt(0) write-drain (~60+ cy/step of serial stall) and the
//    double buffer.
//  - Software-pipelined h reads: the 5 ds_read_b128 for step t+1 are issued
//    immediately after the ds_write of step t; the next body's a-init/x logic
//    runs under the LDS latency with fine-grained lgkmcnt waits.
//  - Unroll x4; x loaded as float4 once per 4 steps, prefetched one full
//    iteration (~4 steps) ahead -> covers HBM-miss latency on the x stream.
//  - Outputs packed in a float4 and stored once per 4 steps (one exec-mask
//    toggle + global_store_dwordx4 per iter instead of a masked store per step).
//  - Lanes 0-59: 3 rows x 20 units; whh = 40 float2 (80 VGPRs) pinned via asm.
//  - Lanes 60-62: output lanes (whh row0=W2, v[0]=b2) -> their g0 IS out[t-1].
//  - exp2-domain activations (log2e pre-folded into weights; c kept 2*log2e-scaled).

#define HID 20
#define ROWS_PER_WAVE 3
#define NTHREADS 64
#define L2E 1.4426950408889634f

typedef float v2f __attribute__((ext_vector_type(2)));

__device__ __forceinline__ float exp2_hw(float v) { return __builtin_amdgcn_exp2f(v); }
__device__ __forceinline__ float rcp_hw(float v)  { return __builtin_amdgcn_rcpf(v); }

// gs = log2e * g   -> sigmoid(g)
__device__ __forceinline__ float sig_s(float gs) {
    return rcp_hw(1.0f + exp2_hw(-gs));
}
// gs2 = 2*log2e*g  -> 2*log2e * tanh(g)  (pre-scaled for the c update)
__device__ __forceinline__ float tanh_2Ls(float gs2) {
    return (2.0f * L2E) - (4.0f * L2E) * rcp_hw(1.0f + exp2_hw(gs2));
}
// cs = 2*log2e*c   -> tanh(c)
__device__ __forceinline__ float tanh_c(float cs) {
    return 1.0f - 2.0f * rcp_hw(1.0f + exp2_hw(cs));
}

__global__ __attribute__((amdgpu_flat_work_group_size(NTHREADS, NTHREADS),
                          amdgpu_waves_per_eu(3, 3)))
void lstm_wave(
        const float* __restrict__ x,     // [B, T]
        const float* __restrict__ W1,    // [20]
        const float* __restrict__ b1,    // [20]
        const float* __restrict__ W_ih,  // [80, 20]
        const float* __restrict__ W_hh,  // [80, 20]
        const float* __restrict__ b_ih,  // [80]
        const float* __restrict__ b_hh,  // [80]
        const float* __restrict__ W2,    // [20]
        const float* __restrict__ b2,    // [1]
        float* __restrict__ out,         // [B, T]
        const int B, const int T)
{
    const int lane = threadIdx.x;
    const int lrow = lane / HID;          // 0..3 (3 = special lanes 60-63)
    const int m    = lane % HID;          // 0..19 (0..3 for lanes 60-63)
    const bool outlane = (lrow == 3) && (m < ROWS_PER_WAVE);   // lanes 60,61,62
    const int rslot = (lrow == 3) ? m : lrow;  // LDS row slot this lane READS (<=3)
    const long rowbase = (long)blockIdx.x * ROWS_PER_WAVE;
    const long row = rowbase + ((lrow == 3) ? (long)((m < 3) ? m : 0) : (long)lrow);
    const long arow = (row < B) ? row : (B - 1);     // safe address for OOB/aux lanes
    const bool ovalid = outlane && (row < B);

    // single buffer: [4 row slots (slot 3 = trash)][20 units]
    __shared__ __align__(16) float hbuf[ROWS_PER_WAVE + 1][HID];

    // ---- phase 1: u, v (NO weight arrays live here; W1/b1 are uniform loads) ----
    float u[4], v[4];
    if (lrow < 3) {
#pragma unroll
        for (int g = 0; g < 4; ++g) {
            const int j = g * HID + m;            // torch gate order i,f,g,o
            const float s = (g == 2) ? (2.0f * L2E) : L2E;
            float uu = 0.f, vv = 0.f;
#pragma unroll
            for (int k = 0; k < HID; ++k) {
                const float wi = W_ih[j * HID + k];
                uu += wi * W1[k];
                vv += wi * b1[k];
            }
            u[g] = s * uu;
            v[g] = s * (vv + b_ih[j] + b_hh[j]);
        }
    } else {
#pragma unroll
        for (int g = 0; g < 4; ++g) { u[g] = 0.f; v[g] = 0.f; }
        v[0] = b2[0];
    }

    // ---- phase 2: whh as 40 float2 pairs (scaled), loaded with low live-set ----
    v2f whh2[4][HID / 2];
    if (lrow < 3) {
#pragma unroll
        for (int g = 0; g < 4; ++g) {
            const int j = g * HID + m;
            const float s = (g == 2) ? (2.0f * L2E) : L2E;
#pragma unroll
            for (int kk = 0; kk < HID / 2; ++kk) {
                v2f w;
                w.x = s * W_hh[j * HID + 2 * kk];
                w.y = s * W_hh[j * HID + 2 * kk + 1];
                whh2[g][kk] = w;
            }
        }
    } else {
#pragma unroll
        for (int kk = 0; kk < HID / 2; ++kk) {
            v2f w; w.x = W2[2 * kk]; w.y = W2[2 * kk + 1];
            whh2[0][kk] = w;
            whh2[1][kk] = (v2f)(0.f);
            whh2[2][kk] = (v2f)(0.f);
            whh2[3][kk] = (v2f)(0.f);
        }
    }

    // Opaque defs: prevent remat of the weight loads into the loop.
#pragma unroll
    for (int g = 0; g < 4; ++g)
#pragma unroll
        for (int kk = 0; kk < HID / 2; ++kk)
            asm volatile("" : "+v"(whh2[g][kk]));

    float cs = 0.f;   // c in 2*log2e-scaled domain
    hbuf[lrow][m] = 0.f;
    if (lane < HID) hbuf[3][lane] = 0.f;   // fully init trash row (NaN hygiene)
    // NOTE: no __syncthreads anywhere — single-wave workgroup, DS ops are
    // executed in wave program order by the LDS pipe.

    const float* __restrict__ xrow = x   + arow * T;
    float* __restrict__       orow = out + arow * T;

    const float4* __restrict__ rdp = (const float4*)&hbuf[rslot][0];
    float* __restrict__        wrp = &hbuf[lrow][m];

    // Pipelined h fragments: F holds h_t while the body computes h_{t+1}.
    float4 F0 = rdp[0], F1 = rdp[1], F2 = rdp[2], F3 = rdp[3], F4 = rdp[4];

    float4 xq = *(const float4*)&xrow[0];   // x[t .. t+3]
    float4 xq_next;
    float4 obuf = make_float4(0.f, 0.f, 0.f, 0.f);  // out[t-4 .. t-1], comp = idx&3

#define FQ(Q, FF)                                                               \
    {   v2f hA; hA.x = (FF).x; hA.y = (FF).y;                                   \
        v2f hB; hB.x = (FF).z; hB.y = (FF).w;                                   \
        a0 = __builtin_elementwise_fma(whh2[0][2*Q],   hA, a0);                 \
        a1 = __builtin_elementwise_fma(whh2[1][2*Q],   hA, a1);                 \
        a2 = __builtin_elementwise_fma(whh2[2][2*Q],   hA, a2);                 \
        a3 = __builtin_elementwise_fma(whh2[3][2*Q],   hA, a3);                 \
        a0 = __builtin_elementwise_fma(whh2[0][2*Q+1], hB, a0);                 \
        a1 = __builtin_elementwise_fma(whh2[1][2*Q+1], hB, a1);                 \
        a2 = __builtin_elementwise_fma(whh2[2][2*Q+1], hB, a2);                 \
        a3 = __builtin_elementwise_fma(whh2[3][2*Q+1], hB, a3);                 }

// One LSTM step. Consumes F (= h_t), writes h_{t+1} to LDS, then immediately
// issues the reads of h_{t+1} back into F for the next step.
#define BODY(XV, OSLOT)                                                         \
    {                                                                           \
        const float xv = (XV);                                                  \
        v2f a0, a1, a2, a3;                                                     \
        a0.x = v[0] + xv * u[0]; a0.y = 0.f;                                    \
        a1.x = v[1] + xv * u[1]; a1.y = 0.f;                                    \
        a2.x = v[2] + xv * u[2]; a2.y = 0.f;                                    \
        a3.x = v[3] + xv * u[3]; a3.y = 0.f;                                    \
        FQ(0, F0) FQ(1, F1) FQ(2, F2) FQ(3, F3) FQ(4, F4)                       \
        const float g0 = a0.x + a0.y;                                           \
        const float g1 = a1.x + a1.y;                                           \
        const float g2 = a2.x + a2.y;                                           \
        const float g3 = a3.x + a3.y;                                           \
        OSLOT = g0;                                                             \
        const float ig  = sig_s(g0);                                            \
        const float fg  = sig_s(g1);                                            \
        const float ggs = tanh_2Ls(g2);                                         \
        const float og  = sig_s(g3);                                            \
        cs = fg * cs + ig * ggs;                                                \
        *wrp = og * tanh_c(cs);                                                 \
        F0 = rdp[0]; F1 = rdp[1]; F2 = rdp[2]; F3 = rdp[3]; F4 = rdp[4];        \
    }

    for (int t = 0; t < T; t += 4) {
        // prefetch next iteration's x a full 4 steps ahead (clamped on last iter)
        const int tp = (t + 4 < T) ? (t + 4) : t;
        xq_next = *(const float4*)&xrow[tp];

        BODY(xq.x, obuf.w)                       // step t   -> out[t-1] (comp 3)
        if (t >= 4 && ovalid) *(float4*)&orow[t - 4] = obuf;   // out[t-4..t-1]
        BODY(xq.y, obuf.x)                       // step t+1 -> out[t]   (comp 0)
        BODY(xq.z, obuf.y)                       // step t+2 -> out[t+1] (comp 1)
        BODY(xq.w, obuf.z)                       // step t+3 -> out[t+2] (comp 2)

        xq = xq_next;
    }

    // epilogue: out[T-1] = b2 + W2 @ h_T ; h_T is in F (reads issued by last body)
    {
        float o = v[0];
        o += whh2[0][0].x * F0.x + whh2[0][0].y * F0.y
           + whh2[0][1].x * F0.z + whh2[0][1].y * F0.w;
        o += whh2[0][2].x * F1.x + whh2[0][2].y * F1.y
           + whh2[0][3].x * F1.z + whh2[0][3].y * F1.w;
        o += whh2[0][4].x * F2.x + whh2[0][4].y * F2.y
           + whh2[0][5].x * F2.z + whh2[0][5].y * F2.w;
        o += whh2[0][6].x * F3.x + whh2[0][6].y * F3.y
           + whh2[0][7].x * F3.z + whh2[0][7].y * F3.w;
        o += whh2[0][8].x * F4.x + whh2[0][8].y * F4.y
           + whh2[0][9].x * F4.z + whh2[0][9].y * F4.w;
        obuf.w = o;                                   // out[T-1] (comp 3)
        if (ovalid) *(float4*)&orow[T - 4] = obuf;    // out[T-4..T-1]
    }
#undef BODY
#undef FQ
}

extern "C" void kernel_launch(void* const* d_in, const int* in_sizes, int n_in,
                              void* d_out, int out_size, void* d_ws, size_t ws_size,
                              hipStream_t stream) {
    (void)n_in; (void)d_ws; (void)ws_size; (void)out_size;
    const float* x    = (const float*)d_in[0];
    const float* W1   = (const float*)d_in[1];
    const float* b1   = (const float*)d_in[2];
    const float* W_ih = (const float*)d_in[3];
    const float* W_hh = (const float*)d_in[4];
    const float* b_ih = (const float*)d_in[5];
    const float* b_hh = (const float*)d_in[6];
    const float* W2   = (const float*)d_in[7];
    const float* b2   = (const float*)d_in[8];
    float* out        = (float*)d_out;

    const int B = 8192;
    const int T = in_sizes[0] / B;  // 2048 (divisible by 4)
    const int grid = (B + ROWS_PER_WAVE - 1) / ROWS_PER_WAVE;  // 2731 single-wave blocks

    lstm_wave<<<grid, NTHREADS, 0, stream>>>(x, W1, b1, W_ih, W_hh, b_ih, b_hh, W2, b2, out, B, T);
}